// Round 7
// baseline (4041.072 us; speedup 1.0000x reference)
//
#include <hip/hip_runtime.h>
#include <stdint.h>

// Bidirectional LSTM.  B=32, T=512, V=32000, D=300, U=300, NT=3.
// R7: recurrence with register-resident weights (B-fragments live in VGPRs
// across all 512 steps), direct L3->register A-fragment loads (agent atomics,
// no LDS staging), in-wave shuffle transpose for the gate phase, c/h state in
// registers.  One __syncthreads per step.  Sync protocol (flags + parity
// double-buffered H, all agent-scope relaxed atomics) carried from R6.

#define BB 32
#define TT 512
#define DD 300
#define UU 300
#define G4 1200   // 4*U
#define NTOK 3

#define KB   10    // blocks per direction
#define UPB  30    // units per block
#define NCOL 120   // gate-cols per block (4*UPB)
#define KTILES 10  // K = 320 (300 padded), 10 tiles of 32
#define HROW 304   // global H row stride (elems), 16B multiple

typedef uint16_t bf16_t;
typedef short  s16x8 __attribute__((ext_vector_type(8)));
typedef float  f32x4 __attribute__((ext_vector_type(4)));

union U8 { unsigned long long q[2]; s16x8 v; };

__device__ __forceinline__ float bf2f(uint16_t u) {
    union { uint32_t i; float f; } v; v.i = ((uint32_t)u) << 16; return v.f;
}
__device__ __forceinline__ uint16_t f2bf(float f) {
    union { uint32_t i; float f; } v; v.f = f;
    uint32_t r = v.i + 0x7fffu + ((v.i >> 16) & 1u);   // RNE
    return (uint16_t)(r >> 16);
}
__device__ __forceinline__ float ldf(const void* base, size_t idx, int f32m) {
    return f32m ? ((const float*)base)[idx]
                : bf2f(((const uint16_t*)base)[idx]);
}

// 4x4 transpose across lane bits 0..1 (quads of 4 lanes). Input: lane c holds
// column c of M (v[r] = M[r][c]); output: lane c holds row c (r[j] = M[c][j]).
__device__ __forceinline__ f32x4 xpose4(f32x4 v, int lane) {
    f32x4 t, w, s, r;
    t[0] = __shfl_xor(v[0], 1); t[1] = __shfl_xor(v[1], 1);
    t[2] = __shfl_xor(v[2], 1); t[3] = __shfl_xor(v[3], 1);
    if ((lane & 1) == 0) { w[0]=v[0]; w[1]=t[0]; w[2]=v[2]; w[3]=t[2]; }
    else                 { w[0]=t[1]; w[1]=v[1]; w[2]=t[3]; w[3]=v[3]; }
    s[0] = __shfl_xor(w[0], 2); s[1] = __shfl_xor(w[1], 2);
    s[2] = __shfl_xor(w[2], 2); s[3] = __shfl_xor(w[3], 2);
    if ((lane & 2) == 0) { r[0]=w[0]; r[1]=w[1]; r[2]=s[0]; r[3]=s[1]; }
    else                 { r[0]=s[2]; r[1]=s[3]; r[2]=w[2]; r[3]=w[3]; }
    return r;
}

__device__ __forceinline__ void gatefn(f32x4 zv, uint2 zp, bool m,
                                       float& c, float& h) {
    float zi = zv[0] + bf2f((uint16_t)(zp.x & 0xffff));
    float zf = zv[1] + bf2f((uint16_t)(zp.x >> 16));
    float zg = zv[2] + bf2f((uint16_t)(zp.y & 0xffff));
    float zo = zv[3] + bf2f((uint16_t)(zp.y >> 16));
    float si = 1.f / (1.f + __expf(-zi));
    float sf = 1.f / (1.f + __expf(-zf));
    float so = 1.f / (1.f + __expf(-zo));
    float tg = tanhf(zg);
    float cn = sf * c + si * tg;
    float hn = so * tanhf(cn);
    if (m) { c = cn; h = hn; }
}

// ---------------------------------------------------------------------------
// Kernel 0: dtype detector (f32 vs bf16 inputs).
// ---------------------------------------------------------------------------
__global__ void detect_dtype(const uint16_t* __restrict__ emb_u16,
                             int* __restrict__ flag) {
    __shared__ float red[256];
    const int tid = threadIdx.x;
    float m = 0.f;
    for (int k = tid; k < 4096; k += 256)
        m = fmaxf(m, fabsf(bf2f(emb_u16[2 * k])));
    red[tid] = m;
    __syncthreads();
    for (int s = 128; s > 0; s >>= 1) {
        if (tid < s) red[tid] = fmaxf(red[tid], red[tid + s]);
        __syncthreads();
    }
    if (tid == 0) flag[0] = (red[0] > 1.0e3f) ? 1 : 0;
}

// ---------------------------------------------------------------------------
// Kernel 1: build WrPT[dir][p][k]: p = 4u+g (gate-interleaved), k-major rows
// of length 304 (k>=300 zero).  WrPT[p][k] = Wr[k][g*300+u].
// ---------------------------------------------------------------------------
__global__ void prep_wrp(const void* __restrict__ Wr_f,
                         const void* __restrict__ Wr_b,
                         bf16_t* __restrict__ WrPT_f,
                         bf16_t* __restrict__ WrPT_b,
                         const int* __restrict__ flagp) {
    const int f32m = *flagp;
    int idx = blockIdx.x * 256 + threadIdx.x;          // over 1200*304
    const void* src = blockIdx.y ? Wr_b : Wr_f;
    bf16_t*     dst = blockIdx.y ? WrPT_b : WrPT_f;
    if (idx < G4 * HROW) {
        int p = idx / HROW;
        int k = idx - p * HROW;
        int u = p >> 2, g = p & 3;
        float v = (k < DD) ? ldf(src, (size_t)k * G4 + g * UU + u, f32m) : 0.f;
        dst[idx] = f2bf(v);
    }
}

// ---------------------------------------------------------------------------
// Kernel 1b: zero H double-buffers and ready flags.
// ---------------------------------------------------------------------------
__global__ void init_state(bf16_t* __restrict__ Hglob, int* __restrict__ flags) {
    int i = blockIdx.x * 256 + threadIdx.x;
    if (i < 2 * 2 * BB * HROW) Hglob[i] = 0;
    if (i < 2 * TT * 16) flags[i] = 0;
}

// ---------------------------------------------------------------------------
// Kernel 2: zx[r][p] = sum_d emb[inputs[r]][d] * Wk[d][j] + b[j], stored at
// permuted col p = 4*(j%300) + j/300.  bf16 out.
// ---------------------------------------------------------------------------
#define BM 64
#define BN 64
#define BK 16
__global__ __launch_bounds__(256) void zx_gemm(
    const int* __restrict__ inputs, const void* __restrict__ emb,
    const void* __restrict__ Wk_f, const void* __restrict__ b_f,
    const void* __restrict__ Wk_b, const void* __restrict__ b_b,
    bf16_t* __restrict__ zxf, bf16_t* __restrict__ zxb,
    const int* __restrict__ flagp) {

    const int f32m = *flagp;
    const int dir = blockIdx.z;
    const void* Wk   = dir ? Wk_b : Wk_f;
    const void* bias = dir ? b_b  : b_f;
    bf16_t*     out  = dir ? zxb  : zxf;

    __shared__ __align__(16) float As[BM][BK + 1];
    __shared__ __align__(16) float Bs[BK][BN];
    __shared__ int rowids[BM];

    const int tid = threadIdx.x;
    const int rowBase = blockIdx.y * BM;
    const int colBase = blockIdx.x * BN;

    if (tid < BM) rowids[tid] = inputs[rowBase + tid];
    __syncthreads();

    float acc[4][4] = {};
    const int tx = tid & 15;
    const int ty = tid >> 4;

    for (int k0 = 0; k0 < DD; k0 += BK) {
#pragma unroll
        for (int i = 0; i < 4; i++) {
            int idx = tid + i * 256;
            int r = idx >> 4, k = idx & 15;
            int kk = k0 + k;
            float v = 0.f;
            if (kk < DD) v = ldf(emb, (size_t)rowids[r] * DD + kk, f32m);
            As[r][k] = v;
        }
#pragma unroll
        for (int i = 0; i < 4; i++) {
            int idx = tid + i * 256;
            int k = idx >> 6, c = idx & 63;
            int kk = k0 + k;
            int col = colBase + c;
            float v = 0.f;
            if (kk < DD && col < G4) v = ldf(Wk, (size_t)kk * G4 + col, f32m);
            Bs[k][c] = v;
        }
        __syncthreads();
#pragma unroll
        for (int k = 0; k < BK; k++) {
            float a0 = As[ty * 4 + 0][k];
            float a1 = As[ty * 4 + 1][k];
            float a2 = As[ty * 4 + 2][k];
            float a3 = As[ty * 4 + 3][k];
            float4 b4 = *(const float4*)&Bs[k][tx * 4];
            acc[0][0] += a0 * b4.x; acc[0][1] += a0 * b4.y; acc[0][2] += a0 * b4.z; acc[0][3] += a0 * b4.w;
            acc[1][0] += a1 * b4.x; acc[1][1] += a1 * b4.y; acc[1][2] += a1 * b4.z; acc[1][3] += a1 * b4.w;
            acc[2][0] += a2 * b4.x; acc[2][1] += a2 * b4.y; acc[2][2] += a2 * b4.z; acc[2][3] += a2 * b4.w;
            acc[3][0] += a3 * b4.x; acc[3][1] += a3 * b4.y; acc[3][2] += a3 * b4.z; acc[3][3] += a3 * b4.w;
        }
        __syncthreads();
    }

#pragma unroll
    for (int i = 0; i < 4; i++) {
        int r = rowBase + ty * 4 + i;
#pragma unroll
        for (int jj = 0; jj < 4; jj++) {
            int col = colBase + tx * 4 + jj;
            if (col < G4) {
                int u = col % UU, g = col / UU;
                int p = 4 * u + g;
                out[(size_t)r * G4 + p] = f2bf(acc[i][jj] + ldf(bias, col, f32m));
            }
        }
    }
}

// ---------------------------------------------------------------------------
// Kernel 3: register-resident MFMA recurrence.  20 blocks (10/dir), 256 thr.
// ---------------------------------------------------------------------------
__global__ __launch_bounds__(256, 1) void lstm_rec3(
    const bf16_t* __restrict__ zxf, const bf16_t* __restrict__ zxb,
    const bf16_t* __restrict__ WrPT_f, const bf16_t* __restrict__ WrPT_b,
    const int* __restrict__ seqlen,
    bf16_t* __restrict__ Hglob, int* __restrict__ flags,
    bf16_t* __restrict__ hf, bf16_t* __restrict__ hb) {

    const int blk = blockIdx.x % KB;
    const int dir = blockIdx.x / KB;
    const bf16_t* zx   = dir ? zxb    : zxf;
    const bf16_t* WrPT = dir ? WrPT_b : WrPT_f;
    bf16_t*       hout = dir ? hb : hf;
    bf16_t*       Hg   = Hglob + (size_t)dir * (2 * BB * HROW);
    int*          fbase = flags + dir * (TT * 16);

    const int tid  = threadIdx.x;
    const int lane = tid & 63;
    const int wv   = tid >> 6;      // wave 0..3 -> cols [32wv, 32wv+32)
    const int q    = lane >> 4;     // quad 0..3
    const int c16  = lane & 15;
    const int n0   = 32 * wv;
    const int k4   = c16 >> 2;      // unit sub-index 0..3
    const int j4   = c16 & 3;       // batch sub-index 0..3
    const int u0   = 8 * wv + k4;   // local unit (tile nt=0), in [0,28)
    const int b0   = 4 * q + j4;    // batch 0..15 (tile m=0); +16 for m=1
    const bool v1  = (u0 + 4 < UPB);            // nt=1 unit valid
    const bool pollme = (lane < KB) && (lane != blk);

    // ---- one-time: B fragments into registers (live across all 512 steps)
    U8 Bf0[KTILES], Bf1[KTILES];
#pragma unroll
    for (int kt = 0; kt < KTILES; kt++) {
        int k0 = 32 * kt + 8 * q;
        int col0 = n0 + c16, col1 = n0 + 16 + c16;
        U8 z; z.q[0] = 0; z.q[1] = 0;
        Bf0[kt] = z; Bf1[kt] = z;
        if (k0 < 304) {
            if (col0 < NCOL)
                Bf0[kt].v = *(const s16x8*)&WrPT[(size_t)(NCOL * blk + col0) * HROW + k0];
            if (col1 < NCOL)
                Bf1[kt].v = *(const s16x8*)&WrPT[(size_t)(NCOL * blk + col1) * HROW + k0];
        }
    }

    // ---- state registers: 4 (batch,unit) pairs per lane
    float c00 = 0.f, c01 = 0.f, c10 = 0.f, c11 = 0.f;
    float h00 = 0.f, h01 = 0.f, h10 = 0.f, h11 = 0.f;
    const int L0 = seqlen[b0];
    const int L1 = seqlen[b0 + 16];

    for (int ts = 0; ts < TT; ts++) {
        const int t = dir ? (TT - 1 - ts) : ts;

        // zx prefetch (block-private, overlaps the flag wait)
        const size_t zr0 = ((size_t)(b0 * TT + t)) * G4 + NCOL * blk;
        const size_t zr1 = ((size_t)((b0 + 16) * TT + t)) * G4 + NCOL * blk;
        uint2 z00 = *(const uint2*)&zx[zr0 + 4 * u0];
        uint2 z10 = *(const uint2*)&zx[zr1 + 4 * u0];
        uint2 z01 = {0, 0}, z11 = {0, 0};
        if (v1) {
            z01 = *(const uint2*)&zx[zr0 + 4 * (u0 + 4)];
            z11 = *(const uint2*)&zx[zr1 + 4 * (u0 + 4)];
        }

        if (ts > 0) {
            int* fl = fbase + (ts - 1) * 16;
            for (;;) {
                int v = pollme ? __hip_atomic_load(&fl[lane], __ATOMIC_RELAXED,
                                                   __HIP_MEMORY_SCOPE_AGENT)
                               : 1;
                if (__all(v != 0)) break;
                __builtin_amdgcn_s_sleep(1);
            }
        }

        // A fragments: direct L3 -> registers (L2-bypassing atomic u64 loads)
        const bf16_t* Hsrc = Hg + (size_t)(ts & 1) * (BB * HROW);
        unsigned long long* A0p = (unsigned long long*)(Hsrc + c16 * HROW);
        unsigned long long* A1p = (unsigned long long*)(Hsrc + (c16 + 16) * HROW);
        U8 Af0[KTILES], Af1[KTILES];
#pragma unroll
        for (int kt = 0; kt < KTILES; kt++) {
            int k0 = 32 * kt + 8 * q;
            if (k0 < 304) {
                int qi = k0 >> 2;
                Af0[kt].q[0] = __hip_atomic_load(&A0p[qi],     __ATOMIC_RELAXED, __HIP_MEMORY_SCOPE_AGENT);
                Af0[kt].q[1] = __hip_atomic_load(&A0p[qi + 1], __ATOMIC_RELAXED, __HIP_MEMORY_SCOPE_AGENT);
                Af1[kt].q[0] = __hip_atomic_load(&A1p[qi],     __ATOMIC_RELAXED, __HIP_MEMORY_SCOPE_AGENT);
                Af1[kt].q[1] = __hip_atomic_load(&A1p[qi + 1], __ATOMIC_RELAXED, __HIP_MEMORY_SCOPE_AGENT);
            } else {
                Af0[kt].q[0] = 0; Af0[kt].q[1] = 0;
                Af1[kt].q[0] = 0; Af1[kt].q[1] = 0;
            }
        }

        // z = H @ Wr_slice (M=32, N=128 over 4 waves, K=320)
        f32x4 acc00 = {0.f,0.f,0.f,0.f}, acc01 = {0.f,0.f,0.f,0.f};
        f32x4 acc10 = {0.f,0.f,0.f,0.f}, acc11 = {0.f,0.f,0.f,0.f};
#pragma unroll
        for (int kt = 0; kt < KTILES; kt++) {
            acc00 = __builtin_amdgcn_mfma_f32_16x16x32_bf16(Af0[kt].v, Bf0[kt].v, acc00, 0, 0, 0);
            acc01 = __builtin_amdgcn_mfma_f32_16x16x32_bf16(Af0[kt].v, Bf1[kt].v, acc01, 0, 0, 0);
            acc10 = __builtin_amdgcn_mfma_f32_16x16x32_bf16(Af1[kt].v, Bf0[kt].v, acc10, 0, 0, 0);
            acc11 = __builtin_amdgcn_mfma_f32_16x16x32_bf16(Af1[kt].v, Bf1[kt].v, acc11, 0, 0, 0);
        }

        // in-wave 4x4 transpose: lane ends with (i,f,g,o) of its (b,u) pairs
        f32x4 t00 = xpose4(acc00, lane);
        f32x4 t01 = xpose4(acc01, lane);
        f32x4 t10 = xpose4(acc10, lane);
        f32x4 t11 = xpose4(acc11, lane);

        const bool m0 = (t < L0);
        const bool m1 = (t < L1);
        gatefn(t00, z00, m0, c00, h00);
        gatefn(t01, z01, m0, c01, h01);
        gatefn(t10, z10, m1, c10, h10);
        gatefn(t11, z11, m1, c11, h11);

        // pair-pack h via shfl_xor(4) (partner holds unit u^1), store u32
        float p00 = __shfl_xor(h00, 4);
        float p01 = __shfl_xor(h01, 4);
        float p10 = __shfl_xor(h10, 4);
        float p11 = __shfl_xor(h11, 4);
        bf16_t* Hdst = Hg + (size_t)((ts + 1) & 1) * (BB * HROW);
        const bool wr = ((lane & 4) == 0);
        const int e0 = UPB * blk + u0;          // even
        const int e1 = e0 + 4;
        if (wr) {
            uint32_t v00 = (uint32_t)f2bf(h00) | ((uint32_t)f2bf(p00) << 16);
            uint32_t v10 = (uint32_t)f2bf(h10) | ((uint32_t)f2bf(p10) << 16);
            *(uint32_t*)&hout[((size_t)(b0 * TT + t)) * UU + e0]        = v00;
            *(uint32_t*)&hout[((size_t)((b0 + 16) * TT + t)) * UU + e0] = v10;
            if (ts < TT - 1) {
                __hip_atomic_store((uint32_t*)&Hdst[b0 * HROW + e0], v00,
                                   __ATOMIC_RELAXED, __HIP_MEMORY_SCOPE_AGENT);
                __hip_atomic_store((uint32_t*)&Hdst[(b0 + 16) * HROW + e0], v10,
                                   __ATOMIC_RELAXED, __HIP_MEMORY_SCOPE_AGENT);
            }
            if (u0 + 5 < UPB) {
                uint32_t v01 = (uint32_t)f2bf(h01) | ((uint32_t)f2bf(p01) << 16);
                uint32_t v11 = (uint32_t)f2bf(h11) | ((uint32_t)f2bf(p11) << 16);
                *(uint32_t*)&hout[((size_t)(b0 * TT + t)) * UU + e1]        = v01;
                *(uint32_t*)&hout[((size_t)((b0 + 16) * TT + t)) * UU + e1] = v11;
                if (ts < TT - 1) {
                    __hip_atomic_store((uint32_t*)&Hdst[b0 * HROW + e1], v01,
                                       __ATOMIC_RELAXED, __HIP_MEMORY_SCOPE_AGENT);
                    __hip_atomic_store((uint32_t*)&Hdst[(b0 + 16) * HROW + e1], v11,
                                       __ATOMIC_RELAXED, __HIP_MEMORY_SCOPE_AGENT);
                }
            }
        }

        if (ts < TT - 1) {
            __syncthreads();   // drains every wave's stores (vmcnt 0) at L3
            if (tid == 0)
                __hip_atomic_store(&fbase[ts * 16 + blk], 1, __ATOMIC_RELAXED,
                                   __HIP_MEMORY_SCOPE_AGENT);
        }
    }
}

// ---------------------------------------------------------------------------
// Kernel 4: out[r] = [hf[r] ; hb[r]] @ fc_W + fc_b.
// ---------------------------------------------------------------------------
__global__ __launch_bounds__(256) void fc_out(
    const bf16_t* __restrict__ hf, const bf16_t* __restrict__ hb,
    const void* __restrict__ fcW, const void* __restrict__ fcb,
    void* __restrict__ out, const int* __restrict__ flagp) {

    const int f32m = *flagp;
    __shared__ float W[2 * UU * NTOK];
    __shared__ float bias[NTOK];
    const int tid = threadIdx.x;
    for (int i = tid; i < 2 * UU * NTOK; i += 256) W[i] = ldf(fcW, i, f32m);
    if (tid < NTOK) bias[tid] = ldf(fcb, tid, f32m);
    __syncthreads();

    const int r = blockIdx.x * 256 + tid;
    const bf16_t* hfr = hf + (size_t)r * UU;
    const bf16_t* hbr = hb + (size_t)r * UU;
    float s0 = bias[0], s1 = bias[1], s2 = bias[2];
    for (int u = 0; u < UU; u++) {
        float f = bf2f(hfr[u]);
        s0 += f * W[u * 3 + 0];
        s1 += f * W[u * 3 + 1];
        s2 += f * W[u * 3 + 2];
    }
    for (int u = 0; u < UU; u++) {
        float f = bf2f(hbr[u]);
        s0 += f * W[(UU + u) * 3 + 0];
        s1 += f * W[(UU + u) * 3 + 1];
        s2 += f * W[(UU + u) * 3 + 2];
    }
    if (f32m) {
        float* o = (float*)out;
        o[(size_t)r * 3 + 0] = s0;
        o[(size_t)r * 3 + 1] = s1;
        o[(size_t)r * 3 + 2] = s2;
    } else {
        bf16_t* o = (bf16_t*)out;
        o[(size_t)r * 3 + 0] = f2bf(s0);
        o[(size_t)r * 3 + 1] = f2bf(s1);
        o[(size_t)r * 3 + 2] = f2bf(s2);
    }
}

// ---------------------------------------------------------------------------
extern "C" void kernel_launch(void* const* d_in, const int* in_sizes, int n_in,
                              void* d_out, int out_size, void* d_ws, size_t ws_size,
                              hipStream_t stream) {
    const int* inputs = (const int*)d_in[0];
    const int* seqlen = (const int*)d_in[1];
    const void* emb  = d_in[2];
    const void* Wk_f = d_in[3];
    const void* Wr_f = d_in[4];
    const void* b_f  = d_in[5];
    const void* Wk_b = d_in[6];
    const void* Wr_b = d_in[7];
    const void* b_b  = d_in[8];
    const void* fcW  = d_in[9];
    const void* fcb  = d_in[10];

    // workspace layout (bytes), 16B aligned
    char* ws = (char*)d_ws;
    int*    flag   = (int*)(ws + 0);                 // 64 B
    int*    flags  = (int*)(ws + 64);                // 2*512*16*4 = 65,536
    bf16_t* Hglob  = (bf16_t*)(ws + 65664);          // 2*2*32*304*2 = 77,824
    bf16_t* WrPT_f = (bf16_t*)(ws + 143488);         // 729,600
    bf16_t* WrPT_b = (bf16_t*)(ws + 873088);         // 729,600
    bf16_t* zxPf   = (bf16_t*)(ws + 1602688);        // 39,321,600
    bf16_t* zxPb   = (bf16_t*)(ws + 40924288);       // 39,321,600
    bf16_t* hfbuf  = (bf16_t*)(ws + 80245888);       // 9,830,400
    bf16_t* hbbuf  = (bf16_t*)(ws + 90076288);       // 9,830,400 -> 99,906,688

    detect_dtype<<<1, 256, 0, stream>>>((const uint16_t*)emb, flag);
    {
        dim3 grid((G4 * HROW + 255) / 256, 2);
        prep_wrp<<<grid, 256, 0, stream>>>(Wr_f, Wr_b, WrPT_f, WrPT_b, flag);
    }
    init_state<<<304, 256, 0, stream>>>(Hglob, flags);
    {
        dim3 grid((G4 + BN - 1) / BN, (BB * TT) / BM, 2);
        zx_gemm<<<grid, 256, 0, stream>>>(inputs, emb, Wk_f, b_f, Wk_b, b_b,
                                          zxPf, zxPb, flag);
    }
    lstm_rec3<<<2 * KB, 256, 0, stream>>>(zxPf, zxPb, WrPT_f, WrPT_b, seqlen,
                                          Hglob, flags, hfbuf, hbbuf);
    fc_out<<<(BB * TT) / 256, 256, 0, stream>>>(hfbuf, hbbuf, fcW, fcb,
                                                d_out, flag);
}

// Round 8
// 2065.128 us; speedup vs baseline: 1.9568x; 1.9568x over previous
//
#include <hip/hip_runtime.h>
#include <stdint.h>

// Bidirectional LSTM.  B=32, T=512, V=32000, D=300, U=300, NT=3.
// R8: rec = R6 staging/comm + R7 register B-frags/xpose/state (hybrid);
//     zx  = MFMA GEMM with pre-transposed WkT (L2-streamed B-frags).

#define BB 32
#define TT 512
#define DD 300
#define UU 300
#define G4 1200   // 4*U
#define NTOK 3

#define KB   10    // rec blocks per direction
#define UPB  30    // units per rec block
#define NCOL 120   // gate-cols per rec block (4*UPB)
#define KTILES 10  // K = 320 (300 padded), 10 tiles of 32
#define HSTR 320   // swizzled LDS row stride (elems)
#define HROW 304   // global H row stride (elems)

#define WKROWS 1280  // WkT padded p-rows
#define WKSTR  320   // WkT padded k-stride

typedef uint16_t bf16_t;
typedef short  s16x8 __attribute__((ext_vector_type(8)));
typedef float  f32x4 __attribute__((ext_vector_type(4)));

union U8 { unsigned long long q[2]; s16x8 v; };

__device__ __forceinline__ float bf2f(uint16_t u) {
    union { uint32_t i; float f; } v; v.i = ((uint32_t)u) << 16; return v.f;
}
__device__ __forceinline__ uint16_t f2bf(float f) {
    union { uint32_t i; float f; } v; v.f = f;
    uint32_t r = v.i + 0x7fffu + ((v.i >> 16) & 1u);   // RNE
    return (uint16_t)(r >> 16);
}
__device__ __forceinline__ float ldf(const void* base, size_t idx, int f32m) {
    return f32m ? ((const float*)base)[idx]
                : bf2f(((const uint16_t*)base)[idx]);
}

// 4x4 transpose across lane bits 0..1 (verified R7)
__device__ __forceinline__ f32x4 xpose4(f32x4 v, int lane) {
    f32x4 t, w, s, r;
    t[0] = __shfl_xor(v[0], 1); t[1] = __shfl_xor(v[1], 1);
    t[2] = __shfl_xor(v[2], 1); t[3] = __shfl_xor(v[3], 1);
    if ((lane & 1) == 0) { w[0]=v[0]; w[1]=t[0]; w[2]=v[2]; w[3]=t[2]; }
    else                 { w[0]=t[1]; w[1]=v[1]; w[2]=t[3]; w[3]=v[3]; }
    s[0] = __shfl_xor(w[0], 2); s[1] = __shfl_xor(w[1], 2);
    s[2] = __shfl_xor(w[2], 2); s[3] = __shfl_xor(w[3], 2);
    if ((lane & 2) == 0) { r[0]=w[0]; r[1]=w[1]; r[2]=s[0]; r[3]=s[1]; }
    else                 { r[0]=s[2]; r[1]=s[3]; r[2]=w[2]; r[3]=w[3]; }
    return r;
}

__device__ __forceinline__ void gatefn(f32x4 zv, uint2 zp, bool m,
                                       float& c, float& h) {
    float zi = zv[0] + bf2f((uint16_t)(zp.x & 0xffff));
    float zf = zv[1] + bf2f((uint16_t)(zp.x >> 16));
    float zg = zv[2] + bf2f((uint16_t)(zp.y & 0xffff));
    float zo = zv[3] + bf2f((uint16_t)(zp.y >> 16));
    float si = 1.f / (1.f + __expf(-zi));
    float sf = 1.f / (1.f + __expf(-zf));
    float so = 1.f / (1.f + __expf(-zo));
    float tg = tanhf(zg);
    float cn = sf * c + si * tg;
    float hn = so * tanhf(cn);
    if (m) { c = cn; h = hn; }
}

// ---------------------------------------------------------------------------
// Kernel 0: dtype detector (f32 vs bf16 inputs).
// ---------------------------------------------------------------------------
__global__ void detect_dtype(const uint16_t* __restrict__ emb_u16,
                             int* __restrict__ flag) {
    __shared__ float red[256];
    const int tid = threadIdx.x;
    float m = 0.f;
    for (int k = tid; k < 4096; k += 256)
        m = fmaxf(m, fabsf(bf2f(emb_u16[2 * k])));
    red[tid] = m;
    __syncthreads();
    for (int s = 128; s > 0; s >>= 1) {
        if (tid < s) red[tid] = fmaxf(red[tid], red[tid + s]);
        __syncthreads();
    }
    if (tid == 0) flag[0] = (red[0] > 1.0e3f) ? 1 : 0;
}

// ---------------------------------------------------------------------------
// Kernel 1: build WrPT[dir][p][k] (rec weights): p = 4u+g, k-major rows of
// length 304 (k>=300 zero).  WrPT[p][k] = Wr[k][g*300+u].
// ---------------------------------------------------------------------------
__global__ void prep_wrp(const void* __restrict__ Wr_f,
                         const void* __restrict__ Wr_b,
                         bf16_t* __restrict__ WrPT_f,
                         bf16_t* __restrict__ WrPT_b,
                         const int* __restrict__ flagp) {
    const int f32m = *flagp;
    int idx = blockIdx.x * 256 + threadIdx.x;          // over 1200*304
    const void* src = blockIdx.y ? Wr_b : Wr_f;
    bf16_t*     dst = blockIdx.y ? WrPT_b : WrPT_f;
    if (idx < G4 * HROW) {
        int p = idx / HROW;
        int k = idx - p * HROW;
        int u = p >> 2, g = p & 3;
        float v = (k < DD) ? ldf(src, (size_t)k * G4 + g * UU + u, f32m) : 0.f;
        dst[idx] = f2bf(v);
    }
}

// ---------------------------------------------------------------------------
// Kernel 1c: build WkT[dir][p][k] (zx weights, permuted+padded) + biasP.
// WkT[p][k] = Wk[k][g*300+u], zero for p>=1200 or k>=300.
// ---------------------------------------------------------------------------
__global__ void prep_wkt(const void* __restrict__ Wk_f, const void* __restrict__ b_f,
                         const void* __restrict__ Wk_b, const void* __restrict__ b_b,
                         bf16_t* __restrict__ WkT, bf16_t* __restrict__ biasP,
                         const int* __restrict__ flagp) {
    const int f32m = *flagp;
    const int dir = blockIdx.y;
    const void* Wk = dir ? Wk_b : Wk_f;
    const void* bs = dir ? b_b  : b_f;
    bf16_t* dst = WkT + (size_t)dir * (WKROWS * WKSTR);
    int idx = blockIdx.x * 256 + threadIdx.x;          // over 1280*320
    if (idx < WKROWS * WKSTR) {
        int p = idx / WKSTR;
        int k = idx - p * WKSTR;
        int u = p >> 2, g = p & 3;
        float v = (p < G4 && k < DD) ? ldf(Wk, (size_t)k * G4 + g * UU + u, f32m)
                                     : 0.f;
        dst[idx] = f2bf(v);
        if (idx < WKROWS) {
            int pp = idx, uu = pp >> 2, gg = pp & 3;
            biasP[dir * WKROWS + idx] =
                (pp < G4) ? f2bf(ldf(bs, gg * UU + uu, f32m)) : (bf16_t)0;
        }
    }
}

// ---------------------------------------------------------------------------
// Kernel 1b: zero H double-buffers and ready flags.
// ---------------------------------------------------------------------------
__global__ void init_state(bf16_t* __restrict__ Hglob, int* __restrict__ flags) {
    int i = blockIdx.x * 256 + threadIdx.x;
    if (i < 2 * 2 * BB * HROW) Hglob[i] = 0;
    if (i < 2 * TT * 16) flags[i] = 0;
}

// ---------------------------------------------------------------------------
// Kernel 2: MFMA zx GEMM.  zx[r][p] = sum_d emb[inputs[r]][d]*WkT[p][d]+b[p].
// Tile M=64 (gathered A in swizzled LDS), N=128 (B-frags direct from WkT/L2).
// grid = (10 Ntiles, 256 Mtiles, 2 dirs), 256 threads.
// ---------------------------------------------------------------------------
#define ZM 64
#define ZN 128
__global__ __launch_bounds__(256, 2) void zx_gemm2(
    const int* __restrict__ inputs, const void* __restrict__ emb,
    const bf16_t* __restrict__ WkTall, const bf16_t* __restrict__ biasP,
    bf16_t* __restrict__ zxf, bf16_t* __restrict__ zxb,
    const int* __restrict__ flagp) {

    const int f32m = *flagp;
    const int dir = blockIdx.z;
    const bf16_t* WkT = WkTall + (size_t)dir * (WKROWS * WKSTR);
    const bf16_t* bp  = biasP + dir * WKROWS;
    bf16_t* out = dir ? zxb : zxf;

    const int tid = threadIdx.x;
    const int pb = blockIdx.x * ZN;           // 0..1152
    const int rowBase = blockIdx.y * ZM;

    __shared__ __align__(16) uint16_t Alds[ZM * HSTR];   // 40,960 B
    __shared__ int rowids[ZM];

    if (tid < ZM) rowids[tid] = inputs[rowBase + tid];
    for (int i = tid; i < ZM * HSTR; i += 256) Alds[i] = 0;
    __syncthreads();

    // stage A gathered: 64 rows x 38 groups of 8, swizzled
    for (int i = tid; i < ZM * 38; i += 256) {
        int r = i / 38, g = i - 38 * r;
        int k0 = g * 8;
        const size_t eb = (size_t)rowids[r] * DD + k0;
        uint16_t tmp[8];
        if (g < 37) {
            if (f32m) {
                const float* ef = (const float*)emb + eb;
#pragma unroll
                for (int e = 0; e < 8; e++) tmp[e] = f2bf(ef[e]);
            } else {
                *(uint4*)tmp = *(const uint4*)((const uint16_t*)emb + eb);
            }
        } else {
#pragma unroll
            for (int e = 0; e < 8; e++) {
                int k = k0 + e;
                tmp[e] = (k < DD)
                    ? (f32m ? f2bf(((const float*)emb)[(size_t)rowids[r] * DD + k])
                            : ((const uint16_t*)emb)[(size_t)rowids[r] * DD + k])
                    : (uint16_t)0;
            }
        }
        *(uint4*)&Alds[r * HSTR + ((g ^ (r & 7)) << 3)] = *(uint4*)tmp;
    }
    __syncthreads();

    const int lane = tid & 63;
    const int wv   = tid >> 6;
    const int q    = lane >> 4;
    const int c16  = lane & 15;
    const int n0   = 32 * wv;
    const int sw7  = c16 & 7;

    f32x4 acc[4][2];
#pragma unroll
    for (int mt = 0; mt < 4; mt++)
        for (int nh = 0; nh < 2; nh++) acc[mt][nh] = (f32x4){0.f,0.f,0.f,0.f};

    const int p0 = pb + n0 + c16;
    const int p1 = p0 + 16;
#pragma unroll
    for (int kt = 0; kt < KTILES; kt++) {
        int k0 = 32 * kt + 8 * q;
        int sw = (((kt * 4 + q) ^ sw7) << 3);
        s16x8 b0 = *(const s16x8*)&WkT[(size_t)p0 * WKSTR + k0];
        s16x8 b1 = *(const s16x8*)&WkT[(size_t)p1 * WKSTR + k0];
#pragma unroll
        for (int mt = 0; mt < 4; mt++) {
            s16x8 af = *(const s16x8*)&Alds[(16 * mt + c16) * HSTR + sw];
            acc[mt][0] = __builtin_amdgcn_mfma_f32_16x16x32_bf16(af, b0, acc[mt][0], 0, 0, 0);
            acc[mt][1] = __builtin_amdgcn_mfma_f32_16x16x32_bf16(af, b1, acc[mt][1], 0, 0, 0);
        }
    }

    __syncthreads();                    // done reading Alds; reuse as C-stage
    float* Cs = (float*)Alds;           // [64][132] f32 = 33,792 B
#pragma unroll
    for (int mt = 0; mt < 4; mt++)
#pragma unroll
        for (int nh = 0; nh < 2; nh++)
#pragma unroll
            for (int r = 0; r < 4; r++)
                Cs[(16 * mt + 4 * q + r) * 132 + n0 + 16 * nh + c16] = acc[mt][nh][r];
    __syncthreads();

    for (int i = tid; i < ZM * (ZN / 2); i += 256) {    // 64x64 u32 pairs
        int r = i >> 6, cc = (i & 63) * 2;
        int p = pb + cc;
        if (p < G4) {
            float v0 = Cs[r * 132 + cc]     + bf2f(bp[p]);
            float v1 = Cs[r * 132 + cc + 1] + bf2f(bp[p + 1]);
            uint32_t pk = (uint32_t)f2bf(v0) | ((uint32_t)f2bf(v1) << 16);
            *(uint32_t*)&out[(size_t)(rowBase + r) * G4 + p] = pk;
        }
    }
}

// ---------------------------------------------------------------------------
// Kernel 3: hybrid MFMA recurrence.  20 blocks (10/dir), 256 thr.
// B-frags + c/h state in registers; H staged via swizzled LDS (coalesced u64
// atomic reload); hstage -> coalesced publish.  3 barriers/step.
// ---------------------------------------------------------------------------
__global__ __launch_bounds__(256, 1) void lstm_rec4(
    const bf16_t* __restrict__ zxf, const bf16_t* __restrict__ zxb,
    const bf16_t* __restrict__ WrPT_f, const bf16_t* __restrict__ WrPT_b,
    const int* __restrict__ seqlen,
    bf16_t* __restrict__ Hglob, int* __restrict__ flags,
    bf16_t* __restrict__ hf, bf16_t* __restrict__ hb) {

    const int blk = blockIdx.x % KB;
    const int dir = blockIdx.x / KB;
    const bf16_t* zx   = dir ? zxb    : zxf;
    const bf16_t* WrPT = dir ? WrPT_b : WrPT_f;
    bf16_t*       hout = dir ? hb : hf;
    bf16_t*       Hg   = Hglob + (size_t)dir * (2 * BB * HROW);
    int*          fbase = flags + dir * (TT * 16);

    __shared__ __align__(16) uint16_t Hlds[BB * HSTR];    // 20,480 B
    __shared__ uint16_t hstage[BB * UPB];                 //  1,920 B

    const int tid  = threadIdx.x;
    const int lane = tid & 63;
    const int wv   = tid >> 6;
    const int q    = lane >> 4;
    const int c16  = lane & 15;
    const int n0   = 32 * wv;
    const int sw7  = c16 & 7;
    const int k4   = c16 >> 2;
    const int j4   = c16 & 3;
    const int u0   = 8 * wv + k4;
    const int b0   = 4 * q + j4;
    const bool v1  = (u0 + 4 < UPB);
    const bool pollme = (lane < KB) && (lane != blk);

    // one-time: zero Hlds (pad groups 38,39 must read 0), B-frags to regs
    for (int i = tid; i < BB * HSTR; i += 256) Hlds[i] = 0;
    U8 Bf0[KTILES], Bf1[KTILES];
#pragma unroll
    for (int kt = 0; kt < KTILES; kt++) {
        int k0 = 32 * kt + 8 * q;
        int col0 = n0 + c16, col1 = n0 + 16 + c16;
        U8 z; z.q[0] = 0; z.q[1] = 0;
        Bf0[kt] = z; Bf1[kt] = z;
        if (k0 < 304) {
            if (col0 < NCOL)
                Bf0[kt].v = *(const s16x8*)&WrPT[(size_t)(NCOL * blk + col0) * HROW + k0];
            if (col1 < NCOL)
                Bf1[kt].v = *(const s16x8*)&WrPT[(size_t)(NCOL * blk + col1) * HROW + k0];
        }
    }
    float c00 = 0.f, c01 = 0.f, c10 = 0.f, c11 = 0.f;
    float h00 = 0.f, h01 = 0.f, h10 = 0.f, h11 = 0.f;
    const int L0 = seqlen[b0];
    const int L1 = seqlen[b0 + 16];
    __syncthreads();

    for (int ts = 0; ts < TT; ts++) {
        const int t = dir ? (TT - 1 - ts) : ts;

        // zx prefetch (overlaps the flag wait)
        const size_t zr0 = ((size_t)(b0 * TT + t)) * G4 + NCOL * blk;
        const size_t zr1 = ((size_t)((b0 + 16) * TT + t)) * G4 + NCOL * blk;
        uint2 z00 = *(const uint2*)&zx[zr0 + 4 * u0];
        uint2 z10 = *(const uint2*)&zx[zr1 + 4 * u0];
        uint2 z01 = {0, 0}, z11 = {0, 0};
        if (v1) {
            z01 = *(const uint2*)&zx[zr0 + 4 * (u0 + 4)];
            z11 = *(const uint2*)&zx[zr1 + 4 * (u0 + 4)];
        }

        if (ts > 0) {
            int* fl = fbase + (ts - 1) * 16;
            for (;;) {
                int v = pollme ? __hip_atomic_load(&fl[lane], __ATOMIC_RELAXED,
                                                   __HIP_MEMORY_SCOPE_AGENT)
                               : 1;
                if (__all(v != 0)) break;
                __builtin_amdgcn_s_sleep(1);
            }
        }

        // coalesced pipelined H reload -> swizzled Hlds (R6-verified)
        const unsigned long long* Hsrc64 =
            (const unsigned long long*)(Hg + (size_t)(ts & 1) * (BB * HROW));
        unsigned long long hv[10];
#pragma unroll
        for (int k = 0; k < 9; k++)
            hv[k] = __hip_atomic_load(&Hsrc64[tid + 256 * k], __ATOMIC_RELAXED,
                                      __HIP_MEMORY_SCOPE_AGENT);
        if (tid < 128)
            hv[9] = __hip_atomic_load(&Hsrc64[2304 + tid], __ATOMIC_RELAXED,
                                      __HIP_MEMORY_SCOPE_AGENT);
#pragma unroll
        for (int k = 0; k < 9; k++) {
            int i = tid + 256 * k;
            int b = i / 76, x = i - 76 * b;
            *(unsigned long long*)
                &Hlds[b * HSTR + ((((x >> 1) ^ (b & 7)) << 3) | ((x & 1) << 2))]
                = hv[k];
        }
        if (tid < 128) {
            int i = 2304 + tid;
            int b = i / 76, x = i - 76 * b;
            *(unsigned long long*)
                &Hlds[b * HSTR + ((((x >> 1) ^ (b & 7)) << 3) | ((x & 1) << 2))]
                = hv[9];
        }
        __syncthreads();                                  // (1)

        // MFMA: A from Hlds (swizzled), B from registers
        f32x4 acc00 = {0.f,0.f,0.f,0.f}, acc01 = {0.f,0.f,0.f,0.f};
        f32x4 acc10 = {0.f,0.f,0.f,0.f}, acc11 = {0.f,0.f,0.f,0.f};
#pragma unroll
        for (int kt = 0; kt < KTILES; kt++) {
            int sw = (((kt * 4 + q) ^ sw7) << 3);
            s16x8 a0 = *(const s16x8*)&Hlds[c16 * HSTR + sw];
            s16x8 a1 = *(const s16x8*)&Hlds[(c16 + 16) * HSTR + sw];
            acc00 = __builtin_amdgcn_mfma_f32_16x16x32_bf16(a0, Bf0[kt].v, acc00, 0, 0, 0);
            acc01 = __builtin_amdgcn_mfma_f32_16x16x32_bf16(a0, Bf1[kt].v, acc01, 0, 0, 0);
            acc10 = __builtin_amdgcn_mfma_f32_16x16x32_bf16(a1, Bf0[kt].v, acc10, 0, 0, 0);
            acc11 = __builtin_amdgcn_mfma_f32_16x16x32_bf16(a1, Bf1[kt].v, acc11, 0, 0, 0);
        }

        // transpose + gates in registers (R7-verified mapping)
        f32x4 t00 = xpose4(acc00, lane);
        f32x4 t01 = xpose4(acc01, lane);
        f32x4 t10 = xpose4(acc10, lane);
        f32x4 t11 = xpose4(acc11, lane);
        const bool m0 = (t < L0);
        const bool m1 = (t < L1);
        gatefn(t00, z00, m0, c00, h00);
        gatefn(t01, z01, m0, c01, h01);
        gatefn(t10, z10, m1, c10, h10);
        gatefn(t11, z11, m1, c11, h11);

        hstage[b0 * UPB + u0]        = f2bf(h00);
        hstage[(b0 + 16) * UPB + u0] = f2bf(h10);
        if (v1) {
            hstage[b0 * UPB + u0 + 4]        = f2bf(h01);
            hstage[(b0 + 16) * UPB + u0 + 4] = f2bf(h11);
        }
        __syncthreads();                                  // (2)

        if (ts < TT - 1) {
            bf16_t* Hdst = Hg + (size_t)((ts + 1) & 1) * (BB * HROW);
            for (int i = tid; i < BB * (UPB / 2); i += 256) {   // 480 pairs
                int b = i / (UPB / 2), k = i - b * (UPB / 2);
                uint32_t val = (uint32_t)hstage[b * UPB + 2 * k] |
                               ((uint32_t)hstage[b * UPB + 2 * k + 1] << 16);
                __hip_atomic_store(
                    (uint32_t*)&Hdst[b * HROW + UPB * blk + 2 * k], val,
                    __ATOMIC_RELAXED, __HIP_MEMORY_SCOPE_AGENT);
            }
            __syncthreads();                              // (3) drain
            if (tid == 0)
                __hip_atomic_store(&fbase[ts * 16 + blk], 1, __ATOMIC_RELAXED,
                                   __HIP_MEMORY_SCOPE_AGENT);
        }

        // private hout stores, off the critical path (coalesced from hstage)
        for (int i = tid; i < BB * (UPB / 2); i += 256) {
            int b = i / (UPB / 2), k = i - b * (UPB / 2);
            uint32_t val = (uint32_t)hstage[b * UPB + 2 * k] |
                           ((uint32_t)hstage[b * UPB + 2 * k + 1] << 16);
            *(uint32_t*)&hout[((size_t)(b * TT + t)) * UU + UPB * blk + 2 * k] = val;
        }
    }
}

// ---------------------------------------------------------------------------
// Kernel 4: out[r] = [hf[r] ; hb[r]] @ fc_W + fc_b.
// ---------------------------------------------------------------------------
__global__ __launch_bounds__(256) void fc_out(
    const bf16_t* __restrict__ hf, const bf16_t* __restrict__ hb,
    const void* __restrict__ fcW, const void* __restrict__ fcb,
    void* __restrict__ out, const int* __restrict__ flagp) {

    const int f32m = *flagp;
    __shared__ float W[2 * UU * NTOK];
    __shared__ float bias[NTOK];
    const int tid = threadIdx.x;
    for (int i = tid; i < 2 * UU * NTOK; i += 256) W[i] = ldf(fcW, i, f32m);
    if (tid < NTOK) bias[tid] = ldf(fcb, tid, f32m);
    __syncthreads();

    const int r = blockIdx.x * 256 + tid;
    const bf16_t* hfr = hf + (size_t)r * UU;
    const bf16_t* hbr = hb + (size_t)r * UU;
    float s0 = bias[0], s1 = bias[1], s2 = bias[2];
    for (int u = 0; u < UU; u++) {
        float f = bf2f(hfr[u]);
        s0 += f * W[u * 3 + 0];
        s1 += f * W[u * 3 + 1];
        s2 += f * W[u * 3 + 2];
    }
    for (int u = 0; u < UU; u++) {
        float f = bf2f(hbr[u]);
        s0 += f * W[(UU + u) * 3 + 0];
        s1 += f * W[(UU + u) * 3 + 1];
        s2 += f * W[(UU + u) * 3 + 2];
    }
    if (f32m) {
        float* o = (float*)out;
        o[(size_t)r * 3 + 0] = s0;
        o[(size_t)r * 3 + 1] = s1;
        o[(size_t)r * 3 + 2] = s2;
    } else {
        bf16_t* o = (bf16_t*)out;
        o[(size_t)r * 3 + 0] = f2bf(s0);
        o[(size_t)r * 3 + 1] = f2bf(s1);
        o[(size_t)r * 3 + 2] = f2bf(s2);
    }
}

// ---------------------------------------------------------------------------
extern "C" void kernel_launch(void* const* d_in, const int* in_sizes, int n_in,
                              void* d_out, int out_size, void* d_ws, size_t ws_size,
                              hipStream_t stream) {
    const int* inputs = (const int*)d_in[0];
    const int* seqlen = (const int*)d_in[1];
    const void* emb  = d_in[2];
    const void* Wk_f = d_in[3];
    const void* Wr_f = d_in[4];
    const void* b_f  = d_in[5];
    const void* Wk_b = d_in[6];
    const void* Wr_b = d_in[7];
    const void* b_b  = d_in[8];
    const void* fcW  = d_in[9];
    const void* fcb  = d_in[10];

    // workspace layout (bytes)
    char* ws = (char*)d_ws;
    int*    flag   = (int*)(ws + 0);                 // 64 B
    int*    flags  = (int*)(ws + 64);                // 65,536
    bf16_t* Hglob  = (bf16_t*)(ws + 65664);          // 77,824
    bf16_t* WrPT_f = (bf16_t*)(ws + 143488);         // 729,600
    bf16_t* WrPT_b = (bf16_t*)(ws + 873088);         // 729,600
    bf16_t* zxPf   = (bf16_t*)(ws + 1602688);        // 39,321,600
    bf16_t* zxPb   = (bf16_t*)(ws + 40924288);       // 39,321,600
    bf16_t* hfbuf  = (bf16_t*)(ws + 80245888);       // 9,830,400
    bf16_t* hbbuf  = (bf16_t*)(ws + 90076288);       // 9,830,400 -> 99,906,688
    // WkT/biasP alias hfbuf: consumed by zx_gemm2 (before rec), clobbered by rec
    bf16_t* WkT    = hfbuf;                          // 2*1280*320*2 = 1,638,400
    bf16_t* biasP  = hfbuf + 2 * WKROWS * WKSTR;     // 2*1280*2 = 5,120

    detect_dtype<<<1, 256, 0, stream>>>((const uint16_t*)emb, flag);
    {
        dim3 grid((G4 * HROW + 255) / 256, 2);
        prep_wrp<<<grid, 256, 0, stream>>>(Wr_f, Wr_b, WrPT_f, WrPT_b, flag);
    }
    {
        dim3 grid((WKROWS * WKSTR + 255) / 256, 2);
        prep_wkt<<<grid, 256, 0, stream>>>(Wk_f, b_f, Wk_b, b_b, WkT, biasP, flag);
    }
    init_state<<<64, 256, 0, stream>>>(Hglob, flags);
    {
        dim3 grid(10, 256, 2);
        zx_gemm2<<<grid, 256, 0, stream>>>(inputs, emb, WkT, biasP,
                                           zxPf, zxPb, flag);
    }
    lstm_rec4<<<2 * KB, 256, 0, stream>>>(zxPf, zxPb, WrPT_f, WrPT_b, seqlen,
                                          Hglob, flags, hfbuf, hbbuf);
    fc_out<<<(BB * TT) / 256, 256, 0, stream>>>(hfbuf, hbbuf, fcW, fcb,
                                                d_out, flag);
}